// Round 3
// baseline (867.741 us; speedup 1.0000x reference)
//
#include <hip/hip_runtime.h>

// out = [N, 2, 128] fp32 : {segment_max[row_ids[n]] - feat[n], feat[n]}
// N = in_sizes[0]/128, R = 50000 (problem constant; used for ws init size).
//
// Timing model (round-2 finding): the harness's per-replay 4.096 GB fill
// shares HBM BW with us; dur ≈ (4.096 GB + our bytes) / ~7 TB/s. Only lever:
// reduce our HBM bytes. Gather runs in REVERSE block order so the tail of
// feat (still LLC-resident after the scatter pass streamed it) is re-read
// from LLC instead of HBM.

__device__ __forceinline__ unsigned int enc_f32(float f) {
    unsigned int u = __float_as_uint(f);
    return (u & 0x80000000u) ? ~u : (u | 0x80000000u);
}
__device__ __forceinline__ float dec_f32(unsigned int u) {
    unsigned int v = (u & 0x80000000u) ? (u & 0x7FFFFFFFu) : ~u;
    return __uint_as_float(v);
}

// Pass 0: zero the encoded segmax table (enc(x) > 0 for every float, so 0 is
// a safe identity; only non-empty segments are ever gathered back).
__global__ void __launch_bounds__(256)
zero_fill(uint4* __restrict__ p, int n4) {
    int i = blockIdx.x * blockDim.x + threadIdx.x;
    int stride = gridDim.x * blockDim.x;
    uint4 z = {0u, 0u, 0u, 0u};
    for (; i < n4; i += stride) p[i] = z;
}

// Pass 1: scatter atomic-max. One thread per float4 chunk: n = i>>5, d4 = i&31.
// Streams feat front-to-back; LLC ends up holding the tail of feat.
__global__ void __launch_bounds__(256)
segmax_scatter(const float4* __restrict__ feat,
               const int* __restrict__ row_ids,
               unsigned int* __restrict__ segmax,  // [R*128] encoded
               int total_chunks) {
    int i = blockIdx.x * blockDim.x + threadIdx.x;
    if (i >= total_chunks) return;
    int n  = i >> 5;
    int d4 = i & 31;
    int row = row_ids[n];
    float4 f = feat[i];
    unsigned int e0 = enc_f32(f.x), e1 = enc_f32(f.y),
                 e2 = enc_f32(f.z), e3 = enc_f32(f.w);
    unsigned int* p = segmax + ((long long)row << 7) + (d4 << 2);
    // Pre-check: location is monotone non-decreasing in encode order, so a
    // skip based on any previously-visible value is always safe.
    uint4 cur = *reinterpret_cast<const uint4*>(p);
    if (cur.x < e0) atomicMax(p + 0, e0);
    if (cur.y < e1) atomicMax(p + 1, e1);
    if (cur.z < e2) atomicMax(p + 2, e2);
    if (cur.w < e3) atomicMax(p + 3, e3);
}

// Pass 2: gather + emit [N][2][128] as [N][64] float4. REVERSE block order:
// first blocks touch the tail of feat, which is the part most likely still
// in the 256 MB LLC after pass 1.
__global__ void __launch_bounds__(256)
gather_emit(const float4* __restrict__ feat,
            const int* __restrict__ row_ids,
            const uint4* __restrict__ segmax,   // [R*32] encoded float4
            float4* __restrict__ out,
            int total_chunks) {
    int blk = gridDim.x - 1 - blockIdx.x;           // reversed block order
    int i = blk * blockDim.x + threadIdx.x;         // coalesced within block
    if (i >= total_chunks) return;
    int n  = i >> 5;
    int d4 = i & 31;
    int row = row_ids[n];
    float4 f = feat[i];
    uint4 m = segmax[((long long)row << 5) + d4];
    float4 r;
    r.x = dec_f32(m.x) - f.x;
    r.y = dec_f32(m.y) - f.y;
    r.z = dec_f32(m.z) - f.z;
    r.w = dec_f32(m.w) - f.w;
    long long ob = ((long long)n << 6) + d4;   // [N][64] float4
    out[ob]      = r;   // residual half  [n][0][d]
    out[ob + 32] = f;   // feat half      [n][1][d]
}

extern "C" void kernel_launch(void* const* d_in, const int* in_sizes, int n_in,
                              void* d_out, int out_size, void* d_ws, size_t ws_size,
                              hipStream_t stream) {
    const float* feat    = (const float*)d_in[0];
    const int*   row_ids = (const int*)d_in[1];
    // d_in[2] = num_rows (device scalar) — R fixed at 50000 per problem.
    const long long R = 50000;
    const int D = 128;
    const int N = in_sizes[0] / D;
    const int total_chunks = N * (D / 4);      // one float4 per thread

    // Zero-init encoded segmax table with our own fill kernel.
    int seg_n4 = (int)(R * D / 4);             // 1.6M uint4 = 25.6 MB
    const int block = 256;
    int fill_grid = 2048;
    zero_fill<<<fill_grid, block, 0, stream>>>((uint4*)d_ws, seg_n4);

    const int grid = (total_chunks + block - 1) / block;

    segmax_scatter<<<grid, block, 0, stream>>>(
        (const float4*)feat, row_ids, (unsigned int*)d_ws, total_chunks);

    gather_emit<<<grid, block, 0, stream>>>(
        (const float4*)feat, row_ids, (const uint4*)d_ws,
        (float4*)d_out, total_chunks);
}

// Round 4
// 687.535 us; speedup vs baseline: 1.2621x; 1.2621x over previous
//
#include <hip/hip_runtime.h>
#include <math.h>

// out = [N, 2, 128] fp32 : {segment_max[row_ids[n]] - feat[n], feat[n]}
// N = 1e6, D = 128, R = 50000.
//
// Round-4 structure: counting-sort grouping instead of atomicMax scatter.
//   K0 zero hist -> K1 histogram -> K2 single-block scan (base,cursor)
//   -> K3 rank-scatter (perm) -> K4 per-row wave max-reduce (no atomics)
//   -> K5 gather+emit.
// fmax is commutative/associative -> output bit-exact regardless of the
// nondeterministic perm order within a row.

#define R_ROWS 50000
#define D_DIM  128

// ---- ws layout (bytes from d_ws base; all 16B-aligned enough for use) ----
//  table  : float [R*D]   @ 0           (25,600,000)
//  hist   : u32   [R]     @ 25,600,000  (200,000)
//  base   : u32   [R]     @ 25,800,000
//  cursor : u32   [R]     @ 26,000,000
//  perm   : int   [N]     @ 26,200,000  (4,000,000)

__global__ void __launch_bounds__(256)
zero_u32(unsigned int* __restrict__ p, int n) {
    int i = blockIdx.x * blockDim.x + threadIdx.x;
    int stride = gridDim.x * blockDim.x;
    for (; i < n; i += stride) p[i] = 0u;
}

__global__ void __launch_bounds__(256)
hist_count(const int* __restrict__ ids, unsigned int* __restrict__ hist, int N) {
    int i = blockIdx.x * blockDim.x + threadIdx.x;
    int stride = gridDim.x * blockDim.x;
    for (; i < N; i += stride) atomicAdd(&hist[ids[i]], 1u);
}

// Single-block exclusive scan of hist[R] -> base, cursor.
__global__ void __launch_bounds__(1024)
scan_block(const unsigned int* __restrict__ hist,
           unsigned int* __restrict__ base,
           unsigned int* __restrict__ cursor) {
    __shared__ unsigned int lds[1024];
    const int t = threadIdx.x;
    const int C = (R_ROWS + 1023) / 1024;   // 49 per thread
    const int j0 = t * C;
    unsigned int tot = 0;
    for (int k = 0; k < C; ++k) {
        int j = j0 + k;
        if (j < R_ROWS) tot += hist[j];
    }
    lds[t] = tot; __syncthreads();
    for (int off = 1; off < 1024; off <<= 1) {
        unsigned int v = (t >= off) ? lds[t - off] : 0u;
        __syncthreads();
        lds[t] += v;
        __syncthreads();
    }
    unsigned int run = (t == 0) ? 0u : lds[t - 1];
    for (int k = 0; k < C; ++k) {
        int j = j0 + k;
        if (j < R_ROWS) {
            base[j] = run;
            cursor[j] = run;
            run += hist[j];
        }
    }
}

__global__ void __launch_bounds__(256)
rank_scatter(const int* __restrict__ ids, unsigned int* __restrict__ cursor,
             int* __restrict__ perm, int N) {
    int i = blockIdx.x * blockDim.x + threadIdx.x;
    int stride = gridDim.x * blockDim.x;
    for (; i < N; i += stride) {
        unsigned int slot = atomicAdd(&cursor[ids[i]], 1u);
        perm[slot] = i;
    }
}

// One wave per segment row: serial loop over members, 64 lanes x float2 = 512B
// per member row; running max in regs; one 512B table write, no atomics.
__global__ void __launch_bounds__(256)
row_reduce(const float* __restrict__ feat,
           const int* __restrict__ perm,
           const unsigned int* __restrict__ base,
           const unsigned int* __restrict__ hist,
           float* __restrict__ table) {
    int r = blockIdx.x * 4 + (threadIdx.x >> 6);
    if (r >= R_ROWS) return;
    int lane = threadIdx.x & 63;
    unsigned int start = base[r];
    unsigned int cnt = hist[r];
    float m0 = -INFINITY, m1 = -INFINITY;
    if (cnt) {
        int n_next = perm[start];
        for (unsigned int k = 0; k < cnt; ++k) {
            int n = n_next;
            if (k + 1 < cnt) n_next = perm[start + k + 1];  // overlap next perm load
            float2 v = *reinterpret_cast<const float2*>(
                feat + (long long)n * D_DIM + lane * 2);
            m0 = fmaxf(m0, v.x);
            m1 = fmaxf(m1, v.y);
        }
        float2 o; o.x = m0; o.y = m1;
        *reinterpret_cast<float2*>(table + (long long)r * D_DIM + lane * 2) = o;
    }
    // cnt==0 rows are never gathered; leave garbage.
}

// Gather + emit [N][2][128] as [N][64] float4.
__global__ void __launch_bounds__(256)
gather_emit(const float4* __restrict__ feat,
            const int* __restrict__ ids,
            const float4* __restrict__ table,   // [R*32] float4
            float4* __restrict__ out,
            int total_chunks) {
    int i = blockIdx.x * blockDim.x + threadIdx.x;
    if (i >= total_chunks) return;
    int n  = i >> 5;
    int d4 = i & 31;
    int row = ids[n];
    float4 f = feat[i];
    float4 m = table[((long long)row << 5) + d4];
    float4 r;
    r.x = m.x - f.x;
    r.y = m.y - f.y;
    r.z = m.z - f.z;
    r.w = m.w - f.w;
    long long ob = ((long long)n << 6) + d4;   // [N][64] float4
    out[ob]      = r;   // residual half [n][0][d]
    out[ob + 32] = f;   // feat half     [n][1][d]
}

extern "C" void kernel_launch(void* const* d_in, const int* in_sizes, int n_in,
                              void* d_out, int out_size, void* d_ws, size_t ws_size,
                              hipStream_t stream) {
    const float* feat = (const float*)d_in[0];
    const int*   ids  = (const int*)d_in[1];
    const int D = D_DIM;
    const int N = in_sizes[0] / D;
    const int total_chunks = N * (D / 4);

    char* ws = (char*)d_ws;
    float*        table  = (float*)(ws + 0);
    unsigned int* hist   = (unsigned int*)(ws + 25600000);
    unsigned int* basep  = (unsigned int*)(ws + 25800000);
    unsigned int* cursor = (unsigned int*)(ws + 26000000);
    int*          perm   = (int*)(ws + 26200000);

    const int block = 256;

    zero_u32<<<256, block, 0, stream>>>(hist, R_ROWS);
    hist_count<<<2048, block, 0, stream>>>(ids, hist, N);
    scan_block<<<1, 1024, 0, stream>>>(hist, basep, cursor);
    rank_scatter<<<2048, block, 0, stream>>>(ids, cursor, perm, N);
    row_reduce<<<(R_ROWS + 3) / 4, block, 0, stream>>>(feat, perm, basep, hist, table);
    gather_emit<<<(total_chunks + block - 1) / block, block, 0, stream>>>(
        (const float4*)feat, ids, (const float4*)table, (float4*)d_out, total_chunks);
}

// Round 6
// 605.325 us; speedup vs baseline: 1.4335x; 1.1358x over previous
//
#include <hip/hip_runtime.h>
#include <math.h>

// out = [N, 2, 128] fp32 : {segment_max[row_ids[n]] - feat[n], feat[n]}
// N = 1e6, D = 128, R = 50000.
//
// Round-6 = round-5 with compile fix: __builtin_nontemporal_store needs a
// native vector type, not HIP's float4 class -> use ext_vector_type(4).
// Structure: counting-sort grouping, then ONE fused kernel that per segment
// row (one wave each): (1) max-reduces member rows, (2) re-reads the (L2-hot)
// member rows and emits both output halves directly.

#define R_ROWS 50000
#define D_DIM  128

typedef float f32x4 __attribute__((ext_vector_type(4)));

// ---- ws layout ----
//  hist   : u32 [R] @ 0
//  base   : u32 [R] @ 200,000
//  cursor : u32 [R] @ 400,000
//  perm   : int [N] @ 600,000

__global__ void __launch_bounds__(256)
zero_u32(unsigned int* __restrict__ p, int n) {
    int i = blockIdx.x * blockDim.x + threadIdx.x;
    int stride = gridDim.x * blockDim.x;
    for (; i < n; i += stride) p[i] = 0u;
}

__global__ void __launch_bounds__(256)
hist_count(const int* __restrict__ ids, unsigned int* __restrict__ hist, int N) {
    int i = blockIdx.x * blockDim.x + threadIdx.x;
    int stride = gridDim.x * blockDim.x;
    for (; i < N; i += stride) atomicAdd(&hist[ids[i]], 1u);
}

// Single-block exclusive scan of hist[R] -> base, cursor.
__global__ void __launch_bounds__(1024)
scan_block(const unsigned int* __restrict__ hist,
           unsigned int* __restrict__ base,
           unsigned int* __restrict__ cursor) {
    __shared__ unsigned int lds[1024];
    const int t = threadIdx.x;
    const int C = (R_ROWS + 1023) / 1024;   // 49 per thread
    const int j0 = t * C;
    unsigned int tot = 0;
    for (int k = 0; k < C; ++k) {
        int j = j0 + k;
        if (j < R_ROWS) tot += hist[j];
    }
    lds[t] = tot; __syncthreads();
    for (int off = 1; off < 1024; off <<= 1) {
        unsigned int v = (t >= off) ? lds[t - off] : 0u;
        __syncthreads();
        lds[t] += v;
        __syncthreads();
    }
    unsigned int run = (t == 0) ? 0u : lds[t - 1];
    for (int k = 0; k < C; ++k) {
        int j = j0 + k;
        if (j < R_ROWS) {
            base[j] = run;
            cursor[j] = run;
            run += hist[j];
        }
    }
}

__global__ void __launch_bounds__(256)
rank_scatter(const int* __restrict__ ids, unsigned int* __restrict__ cursor,
             int* __restrict__ perm, int N) {
    int i = blockIdx.x * blockDim.x + threadIdx.x;
    int stride = gridDim.x * blockDim.x;
    for (; i < N; i += stride) {
        unsigned int slot = atomicAdd(&cursor[ids[i]], 1u);
        perm[slot] = i;
    }
}

// One wave per segment row, two members in flight (half-waves), float4 lanes.
// Loop 1: running max. Combine halves. Loop 2: re-read members (L2-hot) and
// emit residual + feat with nontemporal stores (keep L2 for the re-reads).
__global__ void __launch_bounds__(256)
reduce_emit(const float* __restrict__ feat,
            const int* __restrict__ perm,
            const unsigned int* __restrict__ base,
            const unsigned int* __restrict__ hist,
            float* __restrict__ out) {
    int r = blockIdx.x * 4 + (threadIdx.x >> 6);
    if (r >= R_ROWS) return;
    int lane = threadIdx.x & 63;
    int half = lane >> 5;          // member parity this lane handles
    int col4 = lane & 31;          // float4 column within the 128-float row
    unsigned int start = base[r];
    unsigned int cnt = hist[r];
    if (!cnt) return;              // empty segments never gathered

    f32x4 m = {-INFINITY, -INFINITY, -INFINITY, -INFINITY};
    for (unsigned int k = 0; k < cnt; k += 2) {
        unsigned int kk = k + half;
        if (kk < cnt) {
            int n = perm[start + kk];
            f32x4 v = *reinterpret_cast<const f32x4*>(
                feat + (long long)n * D_DIM + (col4 << 2));
            m.x = fmaxf(m.x, v.x); m.y = fmaxf(m.y, v.y);
            m.z = fmaxf(m.z, v.z); m.w = fmaxf(m.w, v.w);
        }
    }
    // combine the two half-wave partial maxima (same column, lane ^ 32)
    m.x = fmaxf(m.x, __shfl_xor(m.x, 32));
    m.y = fmaxf(m.y, __shfl_xor(m.y, 32));
    m.z = fmaxf(m.z, __shfl_xor(m.z, 32));
    m.w = fmaxf(m.w, __shfl_xor(m.w, 32));

    for (unsigned int k = 0; k < cnt; k += 2) {
        unsigned int kk = k + half;
        if (kk < cnt) {
            int n = perm[start + kk];
            f32x4 v = *reinterpret_cast<const f32x4*>(
                feat + (long long)n * D_DIM + (col4 << 2));   // L2 hit
            f32x4 res = m - v;
            f32x4* o = reinterpret_cast<f32x4*>(out + (long long)n * 2 * D_DIM);
            __builtin_nontemporal_store(res, o + col4);        // [n][0][:]
            __builtin_nontemporal_store(v,   o + 32 + col4);   // [n][1][:]
        }
    }
}

extern "C" void kernel_launch(void* const* d_in, const int* in_sizes, int n_in,
                              void* d_out, int out_size, void* d_ws, size_t ws_size,
                              hipStream_t stream) {
    const float* feat = (const float*)d_in[0];
    const int*   ids  = (const int*)d_in[1];
    const int N = in_sizes[0] / D_DIM;

    char* ws = (char*)d_ws;
    unsigned int* hist   = (unsigned int*)(ws + 0);
    unsigned int* basep  = (unsigned int*)(ws + 200000);
    unsigned int* cursor = (unsigned int*)(ws + 400000);
    int*          perm   = (int*)(ws + 600000);

    const int block = 256;

    zero_u32<<<128, block, 0, stream>>>(hist, R_ROWS);
    hist_count<<<2048, block, 0, stream>>>(ids, hist, N);
    scan_block<<<1, 1024, 0, stream>>>(hist, basep, cursor);
    rank_scatter<<<2048, block, 0, stream>>>(ids, cursor, perm, N);
    reduce_emit<<<(R_ROWS + 3) / 4, block, 0, stream>>>(
        feat, perm, basep, hist, (float*)d_out);
}